// Round 6
// baseline (62.478 us; speedup 1.0000x reference)
//
#include <hip/hip_runtime.h>
#include <math.h>

#define TPB 256          // threads per block
#define QPT 4            // queries per thread  -> 1024 queries per block
#define QSPAN (TPB * QPT)
#define JWIN 256         // shared j-window per block, staged in LDS (3 KB)
#define BIGV 1e10f
#define EPSV 1e-8f

// kernel 1: sq[i] = x*x + y*y (reference rounding) + init packed keys
__global__ void esdf_prep(const float2* __restrict__ pc,
                          float* __restrict__ sq,
                          unsigned long long* __restrict__ key, int n) {
#pragma clang fp contract(off)
    int i = blockIdx.x * blockDim.x + threadIdx.x;
    if (i < n) {
        float2 p = pc[i];
        float xx = p.x * p.x;
        float yy = p.y * p.y;
        sq[i] = xx + yy;
        key[i] = ~0ull;
    }
}

// kernel 2: each thread owns QPT queries; block stages one 256-j window in LDS;
// the 6 ds_read_b128 per 8-j tile are amortized over QPT*8 = 32 pairs.
// Partial argmin merged globally via atomicMin on key = (d2_bits<<32)|j.
__global__ __launch_bounds__(TPB)
void esdf_nn(const float2* __restrict__ pc,
             const float* __restrict__ sq,
             unsigned long long* __restrict__ key, int n) {
#pragma clang fp contract(off)
    const int tid    = threadIdx.x;
    const int jparts = n / JWIN;                  // 64
    const int qblk   = blockIdx.x / jparts;       // 16 query blocks
    const int jpart  = blockIdx.x % jparts;
    const int qbase  = qblk * QSPAN;
    const int jbase  = jpart * JWIN;

    // --- stage j-window into LDS (vector path, coalesced) ---
    __shared__ float4 spc[JWIN / 2];   // 128 float4 = 256 float2 points
    __shared__ float4 ssq[JWIN / 4];   //  64 float4 = 256 sq values
    {
        const float4* pc4 = (const float4*)pc;
        const float4* sq4 = (const float4*)sq;
        if (tid < JWIN / 2) spc[tid] = pc4[(jbase >> 1) + tid];
        else if (tid < JWIN / 2 + JWIN / 4) {
            int t = tid - JWIN / 2;
            ssq[t] = sq4[(jbase >> 2) + t];
        }
    }

    // per-thread query registers
    float xi[QPT], yi[QPT], sqi[QPT];
#pragma unroll
    for (int m = 0; m < QPT; ++m) {
        const int q = qbase + (m << 8) + tid;
        float2 p = pc[q];
        xi[m] = p.x; yi[m] = p.y;
        sqi[m] = sq[q];
    }
    __syncthreads();

    // 2 independent argmin chains per query (k&1); all indices compile-time
    float best[QPT][2];
    int   bi[QPT][2];
#pragma unroll
    for (int m = 0; m < QPT; ++m) {
        best[m][0] = BIGV; best[m][1] = BIGV;
        bi[m][0] = 0;      bi[m][1] = 1;
    }

    for (int jt = 0; jt < JWIN; jt += 8) {
        const int j0 = jbase + jt;                // block-uniform
        float4 p01 = spc[(jt >> 1) + 0];          // ds_read_b128 broadcasts
        float4 p23 = spc[(jt >> 1) + 1];
        float4 p45 = spc[(jt >> 1) + 2];
        float4 p67 = spc[(jt >> 1) + 3];
        float4 sA  = ssq[(jt >> 2) + 0];
        float4 sB  = ssq[(jt >> 2) + 1];
        float xs[8] = {p01.x, p01.z, p23.x, p23.z, p45.x, p45.z, p67.x, p67.z};
        float ys[8] = {p01.y, p01.w, p23.y, p23.w, p45.y, p45.w, p67.y, p67.w};
        float ss[8] = {sA.x, sA.y, sA.z, sA.w, sB.x, sB.y, sB.z, sB.w};

#pragma unroll
        for (int m = 0; m < QPT; ++m) {
            const int qb_m = qbase + (m << 8);    // this m-group's 256-q range
            const int q_m  = qb_m + tid;
            // block-uniform: does [j0, j0+8) intersect [qb_m, qb_m+256)?
            const bool safe = (j0 + 8 <= qb_m) || (j0 >= qb_m + 256);
            if (safe) {
#pragma unroll
                for (int k = 0; k < 8; ++k) {
                    float dot = fmaf(ys[k], yi[m], xs[k] * xi[m]); // BLAS fma order
                    float s   = sqi[m] + ss[k];
                    float d2  = fmaf(-2.0f, dot, s);
                    d2 = fmaxf(d2, 0.0f);
                    const int c = k & 1;
                    if (d2 < best[m][c]) { best[m][c] = d2; bi[m][c] = j0 + k; }
                }
            } else {
#pragma unroll
                for (int k = 0; k < 8; ++k) {
                    float dot = fmaf(ys[k], yi[m], xs[k] * xi[m]);
                    float s   = sqi[m] + ss[k];
                    float d2  = fmaf(-2.0f, dot, s);
                    d2 = fmaxf(d2, 0.0f);
                    bool ok = (j0 + k) != q_m;    // exclude diagonal (ref adds BIG)
                    const int c = k & 1;
                    if (ok && d2 < best[m][c]) { best[m][c] = d2; bi[m][c] = j0 + k; }
                }
            }
        }
    }

    // pack (d2,j) -> u64 key; lexicographic min == numpy argmin w/ low-j ties
#pragma unroll
    for (int m = 0; m < QPT; ++m) {
        unsigned long long k0 =
            ((unsigned long long)__float_as_uint(best[m][0]) << 32) | (unsigned)bi[m][0];
        unsigned long long k1 =
            ((unsigned long long)__float_as_uint(best[m][1]) << 32) | (unsigned)bi[m][1];
        unsigned long long kk = k0 < k1 ? k0 : k1;
        atomicMin(&key[qbase + (m << 8) + tid], kk);
    }
}

// kernel 3: unpack key + epilogue
__global__ void esdf_finalize(const float2* __restrict__ pc,
                              const unsigned long long* __restrict__ key,
                              float* __restrict__ out, int n) {
#pragma clang fp contract(off)
    int q = blockIdx.x * blockDim.x + threadIdx.x;
    if (q >= n) return;
    unsigned long long k = key[q];
    int   ix = (int)(k & 0xffffffffull);
    float b  = __uint_as_float((unsigned)(k >> 32));
    float esdf = sqrtf(b);
    float2 pn = pc[ix];
    float2 pq = pc[q];
    float dx = pq.x - pn.x;
    float dy = pq.y - pn.y;
    float a  = dx * dx;
    float c2 = dy * dy;
    float nrm = sqrtf(a + c2);
    float inv = nrm + EPSV;
    float gx = dx / inv;
    float gy = dy / inv;
    // out = mu(4,N) then lam(3,N), flat
    out[0 * n + q] = gx;
    out[1 * n + q] = -gx;
    out[2 * n + q] = gy;
    out[3 * n + q] = -gy;
    out[4 * n + q] = gx;
    out[5 * n + q] = gy;
    out[6 * n + q] = esdf / 10.0f;
}

extern "C" void kernel_launch(void* const* d_in, const int* in_sizes, int n_in,
                              void* d_out, int out_size, void* d_ws, size_t ws_size,
                              hipStream_t stream) {
    const float2* pc = (const float2*)d_in[0];
    float* out = (float*)d_out;
    const int n = in_sizes[0] / 2;               // 16384

    // ws layout: sq[n] f32 (64KB) | key[n] u64 (128KB)
    float* sq = (float*)d_ws;
    unsigned long long* key = (unsigned long long*)(sq + n);

    const int jparts = n / JWIN;                 // 64
    const int qblks  = n / QSPAN;                // 16

    esdf_prep<<<(n + 255) / 256, 256, 0, stream>>>(pc, sq, key, n);
    esdf_nn<<<qblks * jparts, TPB, 0, stream>>>(pc, sq, key, n);
    esdf_finalize<<<(n + 255) / 256, 256, 0, stream>>>(pc, key, out, n);
}